// Round 14
// baseline (222.700 us; speedup 1.0000x reference)
//
#include <hip/hip_runtime.h>

#define B_ 2
#define L_ 2048
#define C_ 2048
#define H_ 16
#define HKV_ 4
#define D_ 128
#define G_ (H_ / HKV_)
#define TOK_ (B_ * L_)
#define NQKV_ 3072  // H*D + 2*HKV*D

typedef __bf16 bf16;
typedef __bf16 bf16x4 __attribute__((ext_vector_type(4)));
typedef __bf16 bf16x8 __attribute__((ext_vector_type(8)));
typedef float f32x4 __attribute__((ext_vector_type(4)));

__device__ inline void gload16(const void* g, void* l) {
  __builtin_amdgcn_global_load_lds(
      (const __attribute__((address_space(1))) void*)g,
      (__attribute__((address_space(3))) void*)l, 16, 0, 0);
}

// ---------------- fused fp32 -> bf16 conversion (x, Wq, Wk, Wv, Wo) --------
#define N4_X  2097152
#define N4_WQ 1048576
#define N4_WK 262144
#define N4_WV 262144
#define N4_WO 1048576
#define N4_TOT (N4_X + N4_WQ + N4_WK + N4_WV + N4_WO)

__global__ void cvt_all(const float* __restrict__ x, const float* __restrict__ wq,
                        const float* __restrict__ wk, const float* __restrict__ wv,
                        const float* __restrict__ wo, bf16* __restrict__ dst) {
  int stride = gridDim.x * blockDim.x;
  for (int j = blockIdx.x * blockDim.x + threadIdx.x; j < N4_TOT; j += stride) {
    const float* s;
    int off;
    if (j < N4_X) { s = x; off = j; }
    else if (j < N4_X + N4_WQ) { s = wq; off = j - N4_X; }
    else if (j < N4_X + N4_WQ + N4_WK) { s = wk; off = j - (N4_X + N4_WQ); }
    else if (j < N4_X + N4_WQ + N4_WK + N4_WV) { s = wv; off = j - (N4_X + N4_WQ + N4_WK); }
    else { s = wo; off = j - (N4_X + N4_WQ + N4_WK + N4_WV); }
    float4 v = reinterpret_cast<const float4*>(s)[off];
    bf16x4 o = {(bf16)v.x, (bf16)v.y, (bf16)v.z, (bf16)v.w};
    reinterpret_cast<bf16x4*>(dst)[j] = o;
  }
}

// ---------------- GEMM: C[M,N] = A[M,K] @ B[N,K]^T (bf16 in, f32 acc) ------
// 128x128 tile, BK=32, 4 waves. 3-slot LDS ring + counted vmcnt(4).
// (R8 version verbatim — best measured GEMM config.)
template <bool OUT_F32>
__global__ __launch_bounds__(256, 3) void gemm_bt(
    const bf16* __restrict__ A, const bf16* __restrict__ Bm,
    void* __restrict__ Cm, int M, int N, int K) {
  __shared__ __align__(16) bf16 sA[3][128 * 32];
  __shared__ __align__(16) bf16 sB[3][128 * 32];
  const int tid = threadIdx.x;
  const int row0 = blockIdx.x * 128, col0 = blockIdx.y * 128;
  const int wid = tid >> 6, lane = tid & 63;
  const int wr = wid >> 1, wc = wid & 1;
  const int l15 = lane & 15, kk = (lane >> 4) * 8;
  f32x4 acc[4][4] = {};
  const int nk = K / 32;
  const int r0 = tid >> 2, c0 = tid & 3;
  const int r1 = 64 + r0, c1 = c0;
  const int ldsA0 = (wid * 64) * 8, ldsA1 = (256 + wid * 64) * 8;

  auto stage = [&](int kt, int slot) {
    gload16(A + (size_t)(row0 + r0) * K + kt * 32 + c0 * 8, &sA[slot][ldsA0]);
    gload16(A + (size_t)(row0 + r1) * K + kt * 32 + c1 * 8, &sA[slot][ldsA1]);
    gload16(Bm + (size_t)(col0 + r0) * K + kt * 32 + c0 * 8, &sB[slot][ldsA0]);
    gload16(Bm + (size_t)(col0 + r1) * K + kt * 32 + c1 * 8, &sB[slot][ldsA1]);
  };

  stage(0, 0);
  stage(1, 1);
  asm volatile("s_waitcnt vmcnt(4)" ::: "memory");
  __builtin_amdgcn_s_barrier();
  __builtin_amdgcn_sched_barrier(0);

  int slot = 0;
  for (int kt = 0; kt < nk; ++kt) {
    int s2 = slot + 2; if (s2 >= 3) s2 -= 3;
    if (kt + 2 < nk) stage(kt + 2, s2);
    const bf16* cA = sA[slot];
    const bf16* cB = sB[slot];
    bf16x8 af[4], bfr[4];
#pragma unroll
    for (int m = 0; m < 4; ++m)
      af[m] = *reinterpret_cast<const bf16x8*>(cA + (wr * 64 + m * 16 + l15) * 32 + kk);
#pragma unroll
    for (int n = 0; n < 4; ++n)
      bfr[n] = *reinterpret_cast<const bf16x8*>(cB + (wc * 64 + n * 16 + l15) * 32 + kk);
    __builtin_amdgcn_s_setprio(1);
#pragma unroll
    for (int m = 0; m < 4; ++m)
#pragma unroll
      for (int n = 0; n < 4; ++n)
        acc[m][n] = __builtin_amdgcn_mfma_f32_16x16x32_bf16(af[m], bfr[n], acc[m][n], 0, 0, 0);
    __builtin_amdgcn_s_setprio(0);
    if (kt + 2 < nk)
      asm volatile("s_waitcnt vmcnt(4)" ::: "memory");
    else
      asm volatile("s_waitcnt vmcnt(0)" ::: "memory");
    __builtin_amdgcn_s_barrier();
    __builtin_amdgcn_sched_barrier(0);
    slot = (slot + 1 == 3) ? 0 : slot + 1;
  }
#pragma unroll
  for (int m = 0; m < 4; ++m)
#pragma unroll
    for (int n = 0; n < 4; ++n)
#pragma unroll
      for (int r = 0; r < 4; ++r) {
        int row = row0 + wr * 64 + m * 16 + (lane >> 4) * 4 + r;
        int col = col0 + wc * 64 + n * 16 + l15;
        if constexpr (OUT_F32)
          reinterpret_cast<float*>(Cm)[(size_t)row * N + col] = acc[m][n][r];
        else
          reinterpret_cast<bf16*>(Cm)[(size_t)row * N + col] = (bf16)acc[m][n][r];
      }
}

// ---------------- RMSNorm + RoPE for K, relayout to (B, HKV, L, D) ---------
__global__ void k_norm_rope(const bf16* __restrict__ proj,
                            const float* __restrict__ normw,
                            const float* __restrict__ cosb,
                            const float* __restrict__ sinb,
                            bf16* __restrict__ out) {
  int wid = (blockIdx.x * blockDim.x + threadIdx.x) >> 6;
  int lane = threadIdx.x & 63;
  int head = wid & 3, tok = wid >> 2;
  int b = tok / L_, l = tok % L_;
  const bf16* p = proj + (size_t)tok * NQKV_ + H_ * D_ + head * D_;
  float t1 = (float)p[lane];
  float t2 = (float)p[lane + 64];
  float ss = t1 * t1 + t2 * t2;
#pragma unroll
  for (int off = 32; off; off >>= 1) ss += __shfl_xor(ss, off);
  float r = rsqrtf(ss * (1.0f / 128.0f) + 1e-6f);
  float n1 = t1 * r * normw[lane];
  float n2 = t2 * r * normw[lane + 64];
  float c = cosb[l * 64 + lane], s = sinb[l * 64 + lane];
  bf16* q = out + (((size_t)b * HKV_ + head) * L_ + l) * D_;
  q[lane] = (bf16)(n1 * c - n2 * s);
  q[lane + 64] = (bf16)(n2 * c + n1 * s);
}

// ---------------- V transpose (LDS-tiled) ----------------------------------
__global__ __launch_bounds__(256) void v_transpose(const bf16* __restrict__ proj,
                                                   bf16* __restrict__ vt) {
  __shared__ __align__(16) bf16 sT[64 * 136];
  const int t = threadIdx.x;
  const int l0 = blockIdx.x * 64;
  const int bk = blockIdx.y;
  const bf16* src = proj + (size_t)((bk >> 2) * L_ + l0) * NQKV_ + (H_ + HKV_) * D_ + (bk & 3) * D_;
#pragma unroll
  for (int c = 0; c < 4; ++c) {
    int idx = c * 256 + t;
    int l = idx >> 4, dc = idx & 15;
    bf16x8 v = *reinterpret_cast<const bf16x8*>(src + (size_t)l * NQKV_ + dc * 8);
    *reinterpret_cast<bf16x8*>((char*)sT + l * 272 + ((dc ^ (l >> 3)) << 4)) = v;
  }
  __syncthreads();
  bf16* dst = vt + (size_t)bk * D_ * L_ + l0;
#pragma unroll
  for (int c = 0; c < 4; ++c) {
    int idx = c * 256 + t;
    int d = idx >> 3, lg = idx & 7;
    bf16x8 o;
#pragma unroll
    for (int j = 0; j < 8; ++j) {
      int l = lg * 8 + j;
      o[j] = *reinterpret_cast<const bf16*>((char*)sT + l * 272 + (((d >> 3) ^ lg) << 4) + (d & 7) * 2);
    }
    *reinterpret_cast<bf16x8*>(dst + (size_t)d * L_ + lg * 8) = o;
  }
}

// ---------------- Fused flash attention, block-causal, GQA -----------------
// R11 structure (KVBLK=64, dbuf, 80KB) + T15 att[2] rotation: QK^T of tile
// t+1 (MFMA) overlaps softmax of tile t (VALU). K staged 2-ahead, V 1-ahead.
// RACE FIX vs R13: barrier between pre-loop qkt(SM_K0) and the loop (step 0
// stages K2 into SM_K0; without the barrier a fast wave could overwrite K0
// while a slow wave still reads tile-0 fragments).
#define SM_K0 0
#define SM_K1 16384
#define SM_V0 32768
#define SM_V1 49152
#define SM_P  65536
__global__ __launch_bounds__(512, 4) void attn_fused(
    const bf16* __restrict__ QKV,  // (TOK, NQKV) raw projections
    const bf16* __restrict__ Kn,   // (B,HKV,L,D) normed+roped
    const bf16* __restrict__ Vt,   // (B,HKV,D,L)
    const float* __restrict__ qnw,
    const float* __restrict__ cosb, const float* __restrict__ sinb,
    bf16* __restrict__ AO) {  // (B,L,H,D)
  __shared__ __align__(16) char smem[81920];
  const int tid = threadIdx.x;
  const int wid = tid >> 6, lane = tid & 63;
  const int bid = blockIdx.x;
  const int bk = bid & 7;  // same-bk blocks land on same XCD (bid%8)
  const int qt = (bid < 256) ? (bid >> 3) : 63 - ((bid - 256) >> 3);
  const int b = bk >> 2;
  const int hl = wid & 3, qs = wid >> 2;
  const int h = (bk & 3) * G_ + hl;
  const int qrow0 = qt * 32 + qs * 16;
  const int l15 = lane & 15, g4 = lane >> 4, kk = g4 * 8;
  const int swz = (l15 & 7) << 4;

  // ---- fused Q: load + RMSNorm + RoPE (row = qrow0 + l15) ----
  const int qrow = qrow0 + l15;
  const bf16* qsrc = QKV + (size_t)(b * L_ + qrow) * NQKV_ + h * D_;
  float t[4][8];
  float ss = 0.f;
#pragma unroll
  for (int c = 0; c < 4; ++c) {
    bf16x8 v = *reinterpret_cast<const bf16x8*>(qsrc + c * 32 + kk);
#pragma unroll
    for (int j = 0; j < 8; ++j) { t[c][j] = (float)v[j]; ss += t[c][j] * t[c][j]; }
  }

  // staging coordinates (pre-swizzled global sources, linear LDS dest)
  const int kr0 = tid >> 4, kc0 = tid & 15;
  const int kr1 = 32 + kr0;
  const int vr0 = tid >> 3, vc0 = tid & 7;
  const int vr1 = 64 + vr0;
  const bf16* kb = Kn + (size_t)bk * L_ * D_;
  const bf16* vb = Vt + (size_t)bk * D_ * (size_t)L_;
  const bf16* kp0 = kb + (size_t)kr0 * D_ + ((kc0 ^ (kr0 & 7)) * 8);
  const bf16* kp1 = kb + (size_t)kr1 * D_ + ((kc0 ^ (kr1 & 7)) * 8);
  const bf16* vp0 = vb + (size_t)vr0 * L_ + ((vc0 ^ (vr0 & 7)) * 8);
  const bf16* vp1 = vb + (size_t)vr1 * L_ + ((vc0 ^ (vr1 & 7)) * 8);

  const int ntiles = ((qt >> 3) + 1) * 4;  // multiple of 4 (even -> unroll-2)
  // prologue: stage K0,V0 (slot0) and K1 (slot1); fly during Q norm math
  gload16(kp0, smem + SM_K0 + tid * 16);
  gload16(kp1, smem + SM_K0 + 8192 + tid * 16);
  gload16(vp0, smem + SM_V0 + tid * 16);
  gload16(vp1, smem + SM_V0 + 8192 + tid * 16);
  gload16(kp0 + (size_t)64 * D_, smem + SM_K1 + tid * 16);
  gload16(kp1 + (size_t)64 * D_, smem + SM_K1 + 8192 + tid * 16);

  constexpr float SCL = 0.12752650038632816f;  // 128^-0.5 * log2(e)
  ss += __shfl_xor(ss, 16);
  ss += __shfl_xor(ss, 32);
  const float rr = rsqrtf(ss * (1.0f / 128.0f) + 1e-6f);
  bf16x8 qf[4];
#pragma unroll
  for (int c = 0; c < 2; ++c)
#pragma unroll
    for (int j = 0; j < 8; ++j) {
      int i = c * 32 + kk + j;
      float n1 = t[c][j] * rr * qnw[i];
      float n2 = t[c + 2][j] * rr * qnw[i + 64];
      float cs = cosb[qrow * 64 + i], sn = sinb[qrow * 64 + i];
      qf[c][j] = (bf16)((n1 * cs - n2 * sn) * SCL);
      qf[c + 2][j] = (bf16)((n2 * cs + n1 * sn) * SCL);
    }

  // ---- loop-invariant LDS byte addresses ----
  int aK[4], aV[2], aPw[4];
#pragma unroll
  for (int c = 0; c < 4; ++c)
    aK[c] = l15 * 256 + ((((c << 2) + g4) ^ (l15 & 7)) << 4);
#pragma unroll
  for (int hh = 0; hh < 2; ++hh)
    aV[hh] = l15 * 128 + ((((hh << 2) + g4) ^ (l15 & 7)) << 4);
  const int pbase = SM_P + wid * 2048 + l15 * 128;
#pragma unroll
  for (int n = 0; n < 4; ++n)
    aPw[n] = pbase + (((n << 5) + (g4 << 3)) ^ swz);
  const int aPr0 = pbase + ((g4 << 4) ^ swz);
  const int aPr1 = pbase + ((64 + (g4 << 4)) ^ swz);

  f32x4 acc[8] = {};
  float mref = -1e30f, lpart = 0.f;
  f32x4 scur[4];

  auto qkt = [&](int KB, f32x4* sout) {
    __builtin_amdgcn_s_setprio(1);
#pragma unroll
    for (int n = 0; n < 4; ++n) {
      f32x4 st = {};
#pragma unroll
      for (int c = 0; c < 4; ++c) {
        bf16x8 kf = *reinterpret_cast<const bf16x8*>(smem + KB + n * 4096 + aK[c]);
        st = __builtin_amdgcn_mfma_f32_16x16x32_bf16(kf, qf[c], st, 0, 0, 0);
      }
      sout[n] = st;
    }
    __builtin_amdgcn_s_setprio(0);
  };

  __syncthreads();  // K0,V0,K1 staged
  qkt(SM_K0, scur);
  __syncthreads();  // RACE FIX: all waves done reading SM_K0 (tile 0)
                    // before step 0 stages K2 into it

  // step t: QK^T(t+1) from KB_qkt overlaps softmax(t); stage K(t+2)->KB_st,
  // V(t+1)->VB_st; PV(t) from VB_cur. All lifetimes race-free with dbuf.
  auto step = [&](int KB_qkt, int KB_st, int VB_cur, int VB_st, int kt) {
    const bool doK = kt + 2 < ntiles;
    const bool doV = kt + 1 < ntiles;
    if (doK) {
      gload16(kp0 + (size_t)(kt + 2) * 64 * D_, smem + KB_st + tid * 16);
      gload16(kp1 + (size_t)(kt + 2) * 64 * D_, smem + KB_st + 8192 + tid * 16);
    }
    if (doV) {
      gload16(vp0 + (kt + 1) * 64, smem + VB_st + tid * 16);
      gload16(vp1 + (kt + 1) * 64, smem + VB_st + 8192 + tid * 16);
    }
    // --- QK^T for tile t+1 (MFMA pipe; independent of softmax below) ---
    f32x4 snxt[4];
    if (doV) qkt(KB_qkt, snxt);
    // --- defer-max online softmax for tile t (VALU pipe) ---
    float pm = fmaxf(fmaxf(scur[0][0], scur[0][1]), fmaxf(scur[0][2], scur[0][3]));
#pragma unroll
    for (int n = 1; n < 4; ++n)
      pm = fmaxf(pm, fmaxf(fmaxf(scur[n][0], scur[n][1]), fmaxf(scur[n][2], scur[n][3])));
    if (!__all(pm <= mref + 8.f)) {  // rare: true max grew -> reduce, rescale
      pm = fmaxf(pm, __shfl_xor(pm, 16));
      pm = fmaxf(pm, __shfl_xor(pm, 32));
      float mnew = fmaxf(mref, pm);
      float resc = exp2f(mref - mnew);
      mref = mnew;
      lpart *= resc;
#pragma unroll
      for (int f = 0; f < 8; ++f) acc[f] *= resc;
    }
    float qsum[4];
#pragma unroll
    for (int n = 0; n < 4; ++n) {
      float p0 = exp2f(scur[n][0] - mref);
      float p1 = exp2f(scur[n][1] - mref);
      float p2 = exp2f(scur[n][2] - mref);
      float p3 = exp2f(scur[n][3] - mref);
      bf16x4 pw = {(bf16)p0, (bf16)p1, (bf16)p2, (bf16)p3};
      *reinterpret_cast<bf16x4*>(smem + aPw[n]) = pw;
      qsum[n] = (p0 + p1) + (p2 + p3);
    }
    lpart += (qsum[0] + qsum[1]) + (qsum[2] + qsum[3]);
    bf16x8 pf0 = *reinterpret_cast<const bf16x8*>(smem + aPr0);
    bf16x8 pf1 = *reinterpret_cast<const bf16x8*>(smem + aPr1);
    // --- PV(t): O^T = mfma(V^T, P^T) ---
    __builtin_amdgcn_s_setprio(1);
#pragma unroll
    for (int f = 0; f < 8; ++f) {
      bf16x8 vf0 = *reinterpret_cast<const bf16x8*>(smem + VB_cur + f * 2048 + aV[0]);
      acc[f] = __builtin_amdgcn_mfma_f32_16x16x32_bf16(vf0, pf0, acc[f], 0, 0, 0);
      bf16x8 vf1 = *reinterpret_cast<const bf16x8*>(smem + VB_cur + f * 2048 + aV[1]);
      acc[f] = __builtin_amdgcn_mfma_f32_16x16x32_bf16(vf1, pf1, acc[f], 0, 0, 0);
    }
    __builtin_amdgcn_s_setprio(0);
    __syncthreads();  // drains this step's staging; releases P + old slots
    if (doV) {
#pragma unroll
      for (int n = 0; n < 4; ++n) scur[n] = snxt[n];
    }
  };

  for (int kt = 0; kt < ntiles; kt += 2) {
    step(SM_K1, SM_K0, SM_V0, SM_V1, kt);
    step(SM_K0, SM_K1, SM_V1, SM_V0, kt + 1);
  }

  // --- epilogue: reduce row-sum over the 4 lane-groups, packed stores ---
  lpart += __shfl_xor(lpart, 16);
  lpart += __shfl_xor(lpart, 32);
  const float rinv = 1.f / lpart;
  bf16* aop = AO + ((size_t)(b * L_ + qrow0 + l15) * H_ + h) * D_ + (g4 << 2);
#pragma unroll
  for (int f = 0; f < 8; ++f) {
    bf16x4 o = {(bf16)(acc[f][0] * rinv), (bf16)(acc[f][1] * rinv),
                (bf16)(acc[f][2] * rinv), (bf16)(acc[f][3] * rinv)};
    *reinterpret_cast<bf16x4*>(aop + f * 16) = o;
  }
}

// ---------------- launch ----------------
extern "C" void kernel_launch(void* const* d_in, const int* in_sizes, int n_in,
                              void* d_out, int out_size, void* d_ws, size_t ws_size,
                              hipStream_t stream) {
  const float* x = (const float*)d_in[0];
  const float* Wq = (const float*)d_in[1];
  const float* Wk = (const float*)d_in[2];
  const float* Wv = (const float*)d_in[3];
  const float* Wo = (const float*)d_in[4];
  const float* qnw = (const float*)d_in[5];
  const float* knw = (const float*)d_in[6];
  const float* rc = (const float*)d_in[7];
  const float* rs = (const float*)d_in[8];
  float* out = (float*)d_out;

  char* ws = (char*)d_ws;
  bf16* xb = (bf16*)ws;    ws += (size_t)TOK_ * C_ * 2;
  bf16* wqb = (bf16*)ws;   ws += (size_t)(H_ * D_) * C_ * 2;   // wq/wk/wv contiguous!
  bf16* wkb = (bf16*)ws;   ws += (size_t)(HKV_ * D_) * C_ * 2;
  bf16* wvb = (bf16*)ws;   ws += (size_t)(HKV_ * D_) * C_ * 2;
  bf16* wob = (bf16*)ws;   ws += (size_t)C_ * (H_ * D_) * 2;
  bf16* qkv = (bf16*)ws;   ws += (size_t)TOK_ * NQKV_ * 2;
  bf16* Kb = (bf16*)ws;    ws += (size_t)TOK_ * HKV_ * D_ * 2;
  bf16* Vtb = (bf16*)ws;   ws += (size_t)TOK_ * HKV_ * D_ * 2;
  bf16* AOb = xb;  // alias: xb dead after projection GEMM

  cvt_all<<<2048, 256, 0, stream>>>(x, Wq, Wk, Wv, Wo, xb);

  // fused QKV projection: N = 3072 (2-D grid, R8 config)
  gemm_bt<false><<<dim3(TOK_ / 128, NQKV_ / 128), 256, 0, stream>>>(
      xb, wqb, qkv, TOK_, NQKV_, C_);

  k_norm_rope<<<(TOK_ * HKV_) / 4, 256, 0, stream>>>(qkv, knw, rc, rs, Kb);
  v_transpose<<<dim3(L_ / 64, B_ * HKV_), 256, 0, stream>>>(qkv, Vtb);

  attn_fused<<<512, 512, 0, stream>>>(qkv, Kb, Vtb, qnw, rc, rs, AOb);

  gemm_bt<true><<<dim3(TOK_ / 128, C_ / 128), 256, 0, stream>>>(
      AOb, wob, out, TOK_, C_, H_ * D_);
}

// Round 15
// 199.156 us; speedup vs baseline: 1.1182x; 1.1182x over previous
//
#include <hip/hip_runtime.h>

#define B_ 2
#define L_ 2048
#define C_ 2048
#define H_ 16
#define HKV_ 4
#define D_ 128
#define G_ (H_ / HKV_)
#define TOK_ (B_ * L_)
#define NQKV_ 3072  // H*D + 2*HKV*D

typedef __bf16 bf16;
typedef __bf16 bf16x4 __attribute__((ext_vector_type(4)));
typedef __bf16 bf16x8 __attribute__((ext_vector_type(8)));
typedef float f32x4 __attribute__((ext_vector_type(4)));

__device__ inline void gload16(const void* g, void* l) {
  __builtin_amdgcn_global_load_lds(
      (const __attribute__((address_space(1))) void*)g,
      (__attribute__((address_space(3))) void*)l, 16, 0, 0);
}

// ---------------- fused fp32 -> bf16 conversion (x, Wq, Wk, Wv, Wo) --------
#define N4_X  2097152
#define N4_WQ 1048576
#define N4_WK 262144
#define N4_WV 262144
#define N4_WO 1048576
#define N4_TOT (N4_X + N4_WQ + N4_WK + N4_WV + N4_WO)

__global__ void cvt_all(const float* __restrict__ x, const float* __restrict__ wq,
                        const float* __restrict__ wk, const float* __restrict__ wv,
                        const float* __restrict__ wo, bf16* __restrict__ dst) {
  int stride = gridDim.x * blockDim.x;
  for (int j = blockIdx.x * blockDim.x + threadIdx.x; j < N4_TOT; j += stride) {
    const float* s;
    int off;
    if (j < N4_X) { s = x; off = j; }
    else if (j < N4_X + N4_WQ) { s = wq; off = j - N4_X; }
    else if (j < N4_X + N4_WQ + N4_WK) { s = wk; off = j - (N4_X + N4_WQ); }
    else if (j < N4_X + N4_WQ + N4_WK + N4_WV) { s = wv; off = j - (N4_X + N4_WQ + N4_WK); }
    else { s = wo; off = j - (N4_X + N4_WQ + N4_WK + N4_WV); }
    float4 v = reinterpret_cast<const float4*>(s)[off];
    bf16x4 o = {(bf16)v.x, (bf16)v.y, (bf16)v.z, (bf16)v.w};
    reinterpret_cast<bf16x4*>(dst)[j] = o;
  }
}

// ---------------- GEMM: C[M,N] = A[M,K] @ B[N,K]^T (bf16 in, f32 acc) ------
// 128x128 tile, BK=32, 4 waves. 3-slot LDS ring + counted vmcnt(4).
// (R8 version verbatim — best measured GEMM config.)
template <bool OUT_F32>
__global__ __launch_bounds__(256, 3) void gemm_bt(
    const bf16* __restrict__ A, const bf16* __restrict__ Bm,
    void* __restrict__ Cm, int M, int N, int K) {
  __shared__ __align__(16) bf16 sA[3][128 * 32];
  __shared__ __align__(16) bf16 sB[3][128 * 32];
  const int tid = threadIdx.x;
  const int row0 = blockIdx.x * 128, col0 = blockIdx.y * 128;
  const int wid = tid >> 6, lane = tid & 63;
  const int wr = wid >> 1, wc = wid & 1;
  const int l15 = lane & 15, kk = (lane >> 4) * 8;
  f32x4 acc[4][4] = {};
  const int nk = K / 32;
  const int r0 = tid >> 2, c0 = tid & 3;
  const int r1 = 64 + r0, c1 = c0;
  const int ldsA0 = (wid * 64) * 8, ldsA1 = (256 + wid * 64) * 8;

  auto stage = [&](int kt, int slot) {
    gload16(A + (size_t)(row0 + r0) * K + kt * 32 + c0 * 8, &sA[slot][ldsA0]);
    gload16(A + (size_t)(row0 + r1) * K + kt * 32 + c1 * 8, &sA[slot][ldsA1]);
    gload16(Bm + (size_t)(col0 + r0) * K + kt * 32 + c0 * 8, &sB[slot][ldsA0]);
    gload16(Bm + (size_t)(col0 + r1) * K + kt * 32 + c1 * 8, &sB[slot][ldsA1]);
  };

  stage(0, 0);
  stage(1, 1);
  asm volatile("s_waitcnt vmcnt(4)" ::: "memory");
  __builtin_amdgcn_s_barrier();
  __builtin_amdgcn_sched_barrier(0);

  int slot = 0;
  for (int kt = 0; kt < nk; ++kt) {
    int s2 = slot + 2; if (s2 >= 3) s2 -= 3;
    if (kt + 2 < nk) stage(kt + 2, s2);
    const bf16* cA = sA[slot];
    const bf16* cB = sB[slot];
    bf16x8 af[4], bfr[4];
#pragma unroll
    for (int m = 0; m < 4; ++m)
      af[m] = *reinterpret_cast<const bf16x8*>(cA + (wr * 64 + m * 16 + l15) * 32 + kk);
#pragma unroll
    for (int n = 0; n < 4; ++n)
      bfr[n] = *reinterpret_cast<const bf16x8*>(cB + (wc * 64 + n * 16 + l15) * 32 + kk);
    __builtin_amdgcn_s_setprio(1);
#pragma unroll
    for (int m = 0; m < 4; ++m)
#pragma unroll
      for (int n = 0; n < 4; ++n)
        acc[m][n] = __builtin_amdgcn_mfma_f32_16x16x32_bf16(af[m], bfr[n], acc[m][n], 0, 0, 0);
    __builtin_amdgcn_s_setprio(0);
    if (kt + 2 < nk)
      asm volatile("s_waitcnt vmcnt(4)" ::: "memory");
    else
      asm volatile("s_waitcnt vmcnt(0)" ::: "memory");
    __builtin_amdgcn_s_barrier();
    __builtin_amdgcn_sched_barrier(0);
    slot = (slot + 1 == 3) ? 0 : slot + 1;
  }
#pragma unroll
  for (int m = 0; m < 4; ++m)
#pragma unroll
    for (int n = 0; n < 4; ++n)
#pragma unroll
      for (int r = 0; r < 4; ++r) {
        int row = row0 + wr * 64 + m * 16 + (lane >> 4) * 4 + r;
        int col = col0 + wc * 64 + n * 16 + l15;
        if constexpr (OUT_F32)
          reinterpret_cast<float*>(Cm)[(size_t)row * N + col] = acc[m][n][r];
        else
          reinterpret_cast<bf16*>(Cm)[(size_t)row * N + col] = (bf16)acc[m][n][r];
      }
}

// ------- Fused K-norm/RoPE + V-transpose (both read qkv only) --------------
// blocks [0, 4096): k_norm_rope (4 waves/block, one (tok,head) per wave)
// blocks [4096, 4352): v_transpose (bid-4096 -> (l0, bk))
__global__ __launch_bounds__(256) void knorm_vtrans(
    const bf16* __restrict__ proj,   // (TOK, NQKV)
    const float* __restrict__ normw,
    const float* __restrict__ cosb, const float* __restrict__ sinb,
    bf16* __restrict__ kout,         // (B,HKV,L,D)
    bf16* __restrict__ vt) {         // (B,HKV,D,L)
  __shared__ __align__(16) bf16 sT[64 * 136];
  if (blockIdx.x < 4096) {
    int wid = (blockIdx.x * blockDim.x + threadIdx.x) >> 6;
    int lane = threadIdx.x & 63;
    int head = wid & 3, tok = wid >> 2;
    int b = tok / L_, l = tok % L_;
    const bf16* p = proj + (size_t)tok * NQKV_ + H_ * D_ + head * D_;
    float t1 = (float)p[lane];
    float t2 = (float)p[lane + 64];
    float ss = t1 * t1 + t2 * t2;
#pragma unroll
    for (int off = 32; off; off >>= 1) ss += __shfl_xor(ss, off);
    float r = rsqrtf(ss * (1.0f / 128.0f) + 1e-6f);
    float n1 = t1 * r * normw[lane];
    float n2 = t2 * r * normw[lane + 64];
    float c = cosb[l * 64 + lane], s = sinb[l * 64 + lane];
    bf16* q = kout + (((size_t)b * HKV_ + head) * L_ + l) * D_;
    q[lane] = (bf16)(n1 * c - n2 * s);
    q[lane + 64] = (bf16)(n2 * c + n1 * s);
    return;
  }
  const int vbid = blockIdx.x - 4096;
  const int t = threadIdx.x;
  const int l0 = (vbid & 31) * 64;
  const int bk = vbid >> 5;  // b*HKV+h
  const bf16* src = proj + (size_t)((bk >> 2) * L_ + l0) * NQKV_ + (H_ + HKV_) * D_ + (bk & 3) * D_;
#pragma unroll
  for (int c = 0; c < 4; ++c) {
    int idx = c * 256 + t;
    int l = idx >> 4, dc = idx & 15;
    bf16x8 v = *reinterpret_cast<const bf16x8*>(src + (size_t)l * NQKV_ + dc * 8);
    *reinterpret_cast<bf16x8*>((char*)sT + l * 272 + ((dc ^ (l >> 3)) << 4)) = v;
  }
  __syncthreads();
  bf16* dst = vt + (size_t)bk * D_ * L_ + l0;
#pragma unroll
  for (int c = 0; c < 4; ++c) {
    int idx = c * 256 + t;
    int d = idx >> 3, lg = idx & 7;
    bf16x8 o;
#pragma unroll
    for (int j = 0; j < 8; ++j) {
      int l = lg * 8 + j;
      o[j] = *reinterpret_cast<const bf16*>((char*)sT + l * 272 + (((d >> 3) ^ lg) << 4) + (d & 7) * 2);
    }
    *reinterpret_cast<bf16x8*>(dst + (size_t)d * L_ + lg * 8) = o;
  }
}

// ---------------- Fused flash attention, block-causal, GQA -----------------
// R11 version verbatim (best measured: 76.0 us). KVBLK=64, dbuf, 80KB LDS,
// swapped QK^T, defer-max scalar softmax, early per-quarter P-writes,
// tree-summed lpart.
#define SM_K0 0
#define SM_K1 16384
#define SM_V0 32768
#define SM_V1 49152
#define SM_P  65536
__global__ __launch_bounds__(512, 4) void attn_fused(
    const bf16* __restrict__ QKV,  // (TOK, NQKV) raw projections
    const bf16* __restrict__ Kn,   // (B,HKV,L,D) normed+roped
    const bf16* __restrict__ Vt,   // (B,HKV,D,L)
    const float* __restrict__ qnw,
    const float* __restrict__ cosb, const float* __restrict__ sinb,
    bf16* __restrict__ AO) {  // (B,L,H,D)
  __shared__ __align__(16) char smem[81920];
  const int tid = threadIdx.x;
  const int wid = tid >> 6, lane = tid & 63;
  const int bid = blockIdx.x;
  const int bk = bid & 7;  // same-bk blocks land on same XCD (bid%8)
  const int qt = (bid < 256) ? (bid >> 3) : 63 - ((bid - 256) >> 3);
  const int b = bk >> 2;
  const int hl = wid & 3, qs = wid >> 2;
  const int h = (bk & 3) * G_ + hl;
  const int qrow0 = qt * 32 + qs * 16;
  const int l15 = lane & 15, g4 = lane >> 4, kk = g4 * 8;
  const int swz = (l15 & 7) << 4;

  // ---- fused Q: load + RMSNorm + RoPE (row = qrow0 + l15) ----
  const int qrow = qrow0 + l15;
  const bf16* qsrc = QKV + (size_t)(b * L_ + qrow) * NQKV_ + h * D_;
  float t[4][8];
  float ss = 0.f;
#pragma unroll
  for (int c = 0; c < 4; ++c) {
    bf16x8 v = *reinterpret_cast<const bf16x8*>(qsrc + c * 32 + kk);
#pragma unroll
    for (int j = 0; j < 8; ++j) { t[c][j] = (float)v[j]; ss += t[c][j] * t[c][j]; }
  }

  // staging coordinates (pre-swizzled global sources, linear LDS dest)
  const int kr0 = tid >> 4, kc0 = tid & 15;
  const int kr1 = 32 + kr0;
  const int vr0 = tid >> 3, vc0 = tid & 7;
  const int vr1 = 64 + vr0;
  const bf16* kb = Kn + (size_t)bk * L_ * D_;
  const bf16* vb = Vt + (size_t)bk * D_ * (size_t)L_;
  const bf16* kp0 = kb + (size_t)kr0 * D_ + ((kc0 ^ (kr0 & 7)) * 8);
  const bf16* kp1 = kb + (size_t)kr1 * D_ + ((kc0 ^ (kr1 & 7)) * 8);
  const bf16* vp0 = vb + (size_t)vr0 * L_ + ((vc0 ^ (vr0 & 7)) * 8);
  const bf16* vp1 = vb + (size_t)vr1 * L_ + ((vc0 ^ (vr1 & 7)) * 8);

  const int ntiles = ((qt >> 3) + 1) * 4;
  gload16(kp0, smem + SM_K0 + tid * 16);
  gload16(kp1, smem + SM_K0 + 8192 + tid * 16);
  gload16(vp0, smem + SM_V0 + tid * 16);
  gload16(vp1, smem + SM_V0 + 8192 + tid * 16);

  constexpr float SCL = 0.12752650038632816f;  // 128^-0.5 * log2(e)
  ss += __shfl_xor(ss, 16);
  ss += __shfl_xor(ss, 32);
  const float rr = rsqrtf(ss * (1.0f / 128.0f) + 1e-6f);
  bf16x8 qf[4];
#pragma unroll
  for (int c = 0; c < 2; ++c)
#pragma unroll
    for (int j = 0; j < 8; ++j) {
      int i = c * 32 + kk + j;
      float n1 = t[c][j] * rr * qnw[i];
      float n2 = t[c + 2][j] * rr * qnw[i + 64];
      float cs = cosb[qrow * 64 + i], sn = sinb[qrow * 64 + i];
      qf[c][j] = (bf16)((n1 * cs - n2 * sn) * SCL);
      qf[c + 2][j] = (bf16)((n2 * cs + n1 * sn) * SCL);
    }

  // ---- loop-invariant LDS byte addresses ----
  int aK[4], aV[2], aPw[4];
#pragma unroll
  for (int c = 0; c < 4; ++c)
    aK[c] = l15 * 256 + ((((c << 2) + g4) ^ (l15 & 7)) << 4);
#pragma unroll
  for (int hh = 0; hh < 2; ++hh)
    aV[hh] = l15 * 128 + ((((hh << 2) + g4) ^ (l15 & 7)) << 4);
  const int pbase = SM_P + wid * 2048 + l15 * 128;
#pragma unroll
  for (int n = 0; n < 4; ++n)
    aPw[n] = pbase + (((n << 5) + (g4 << 3)) ^ swz);
  const int aPr0 = pbase + ((g4 << 4) ^ swz);
  const int aPr1 = pbase + ((64 + (g4 << 4)) ^ swz);

  f32x4 acc[8] = {};
  float mref = -1e30f, lpart = 0.f;

  __syncthreads();  // tile 0 staged

  auto tile_step = [&](int KB, int VB, int KBn, int VBn, int ktNext, bool doPref) {
    if (doPref) {
      gload16(kp0 + (size_t)ktNext * 64 * D_, smem + KBn + tid * 16);
      gload16(kp1 + (size_t)ktNext * 64 * D_, smem + KBn + 8192 + tid * 16);
      gload16(vp0 + ktNext * 64, smem + VBn + tid * 16);
      gload16(vp1 + ktNext * 64, smem + VBn + 8192 + tid * 16);
    }
    // --- swapped QK^T: s[n][r] = Sscaled[qrow=l15][key=16n+4g4+r] ---
    f32x4 s[4];
    __builtin_amdgcn_s_setprio(1);
#pragma unroll
    for (int n = 0; n < 4; ++n) {
      f32x4 st = {};
#pragma unroll
      for (int c = 0; c < 4; ++c) {
        bf16x8 kf = *reinterpret_cast<const bf16x8*>(smem + KB + n * 4096 + aK[c]);
        st = __builtin_amdgcn_mfma_f32_16x16x32_bf16(kf, qf[c], st, 0, 0, 0);
      }
      s[n] = st;
    }
    __builtin_amdgcn_s_setprio(0);
    // --- defer-max online softmax (scalar per lane: one q-row) ---
    float pm = fmaxf(fmaxf(s[0][0], s[0][1]), fmaxf(s[0][2], s[0][3]));
#pragma unroll
    for (int n = 1; n < 4; ++n)
      pm = fmaxf(pm, fmaxf(fmaxf(s[n][0], s[n][1]), fmaxf(s[n][2], s[n][3])));
    if (!__all(pm <= mref + 8.f)) {  // rare: true max grew -> reduce, rescale
      pm = fmaxf(pm, __shfl_xor(pm, 16));
      pm = fmaxf(pm, __shfl_xor(pm, 32));
      float mnew = fmaxf(mref, pm);
      float resc = exp2f(mref - mnew);
      mref = mnew;
      lpart *= resc;
#pragma unroll
      for (int f = 0; f < 8; ++f) acc[f] *= resc;
    }
    // --- exp2 + immediate per-quarter P write + tree row-sum ---
    float qsum[4];
#pragma unroll
    for (int n = 0; n < 4; ++n) {
      float p0 = exp2f(s[n][0] - mref);
      float p1 = exp2f(s[n][1] - mref);
      float p2 = exp2f(s[n][2] - mref);
      float p3 = exp2f(s[n][3] - mref);
      bf16x4 pw = {(bf16)p0, (bf16)p1, (bf16)p2, (bf16)p3};
      *reinterpret_cast<bf16x4*>(smem + aPw[n]) = pw;
      qsum[n] = (p0 + p1) + (p2 + p3);
    }
    lpart += (qsum[0] + qsum[1]) + (qsum[2] + qsum[3]);
    bf16x8 pf0 = *reinterpret_cast<const bf16x8*>(smem + aPr0);
    bf16x8 pf1 = *reinterpret_cast<const bf16x8*>(smem + aPr1);
    // --- PV: O^T = mfma(V^T, P^T) ---
    __builtin_amdgcn_s_setprio(1);
#pragma unroll
    for (int f = 0; f < 8; ++f) {
      bf16x8 vf0 = *reinterpret_cast<const bf16x8*>(smem + VB + f * 2048 + aV[0]);
      acc[f] = __builtin_amdgcn_mfma_f32_16x16x32_bf16(vf0, pf0, acc[f], 0, 0, 0);
      bf16x8 vf1 = *reinterpret_cast<const bf16x8*>(smem + VB + f * 2048 + aV[1]);
      acc[f] = __builtin_amdgcn_mfma_f32_16x16x32_bf16(vf1, pf1, acc[f], 0, 0, 0);
    }
    __builtin_amdgcn_s_setprio(0);
    __syncthreads();
  };

  for (int kt = 0; kt < ntiles; kt += 2) {
    tile_step(SM_K0, SM_V0, SM_K1, SM_V1, kt + 1, true);
    tile_step(SM_K1, SM_V1, SM_K0, SM_V0, kt + 2, kt + 2 < ntiles);
  }

  // --- epilogue ---
  lpart += __shfl_xor(lpart, 16);
  lpart += __shfl_xor(lpart, 32);
  const float rinv = 1.f / lpart;
  bf16* aop = AO + ((size_t)(b * L_ + qrow0 + l15) * H_ + h) * D_ + (g4 << 2);
#pragma unroll
  for (int f = 0; f < 8; ++f) {
    bf16x4 o = {(bf16)(acc[f][0] * rinv), (bf16)(acc[f][1] * rinv),
                (bf16)(acc[f][2] * rinv), (bf16)(acc[f][3] * rinv)};
    *reinterpret_cast<bf16x4*>(aop + f * 16) = o;
  }
}

// ---------------- launch ----------------
extern "C" void kernel_launch(void* const* d_in, const int* in_sizes, int n_in,
                              void* d_out, int out_size, void* d_ws, size_t ws_size,
                              hipStream_t stream) {
  const float* x = (const float*)d_in[0];
  const float* Wq = (const float*)d_in[1];
  const float* Wk = (const float*)d_in[2];
  const float* Wv = (const float*)d_in[3];
  const float* Wo = (const float*)d_in[4];
  const float* qnw = (const float*)d_in[5];
  const float* knw = (const float*)d_in[6];
  const float* rc = (const float*)d_in[7];
  const float* rs = (const float*)d_in[8];
  float* out = (float*)d_out;

  char* ws = (char*)d_ws;
  bf16* xb = (bf16*)ws;    ws += (size_t)TOK_ * C_ * 2;
  bf16* wqb = (bf16*)ws;   ws += (size_t)(H_ * D_) * C_ * 2;   // wq/wk/wv contiguous!
  bf16* wkb = (bf16*)ws;   ws += (size_t)(HKV_ * D_) * C_ * 2;
  bf16* wvb = (bf16*)ws;   ws += (size_t)(HKV_ * D_) * C_ * 2;
  bf16* wob = (bf16*)ws;   ws += (size_t)C_ * (H_ * D_) * 2;
  bf16* qkv = (bf16*)ws;   ws += (size_t)TOK_ * NQKV_ * 2;
  bf16* Kb = (bf16*)ws;    ws += (size_t)TOK_ * HKV_ * D_ * 2;
  bf16* Vtb = (bf16*)ws;   ws += (size_t)TOK_ * HKV_ * D_ * 2;
  bf16* AOb = xb;  // alias: xb dead after projection GEMM

  cvt_all<<<2048, 256, 0, stream>>>(x, Wq, Wk, Wv, Wo, xb);

  // fused QKV projection: N = 3072 (2-D grid, R8 config)
  gemm_bt<false><<<dim3(TOK_ / 128, NQKV_ / 128), 256, 0, stream>>>(
      xb, wqb, qkv, TOK_, NQKV_, C_);

  // fused K-norm/RoPE (4096 blocks) + V-transpose (256 blocks)
  knorm_vtrans<<<4352, 256, 0, stream>>>(qkv, knw, rc, rs, Kb, Vtb);

  attn_fused<<<512, 512, 0, stream>>>(qkv, Kb, Vtb, qnw, rc, rs, AOb);

  gemm_bt<true><<<dim3(TOK_ / 128, C_ / 128), 256, 0, stream>>>(
      AOb, wob, out, TOK_, C_, H_ * D_);
}

// Round 16
// 197.493 us; speedup vs baseline: 1.1276x; 1.0084x over previous
//
#include <hip/hip_runtime.h>

#define B_ 2
#define L_ 2048
#define C_ 2048
#define H_ 16
#define HKV_ 4
#define D_ 128
#define G_ (H_ / HKV_)
#define TOK_ (B_ * L_)
#define NQKV_ 3072  // H*D + 2*HKV*D

typedef __bf16 bf16;
typedef __bf16 bf16x2 __attribute__((ext_vector_type(2)));
typedef __bf16 bf16x4 __attribute__((ext_vector_type(4)));
typedef __bf16 bf16x8 __attribute__((ext_vector_type(8)));
typedef float f32x4 __attribute__((ext_vector_type(4)));

__device__ inline void gload16(const void* g, void* l) {
  __builtin_amdgcn_global_load_lds(
      (const __attribute__((address_space(1))) void*)g,
      (__attribute__((address_space(3))) void*)l, 16, 0, 0);
}

// ---------------- fused fp32 -> bf16 conversion (x, Wq, Wk, Wv, Wo) --------
#define N4_X  2097152
#define N4_WQ 1048576
#define N4_WK 262144
#define N4_WV 262144
#define N4_WO 1048576
#define N4_TOT (N4_X + N4_WQ + N4_WK + N4_WV + N4_WO)

__global__ void cvt_all(const float* __restrict__ x, const float* __restrict__ wq,
                        const float* __restrict__ wk, const float* __restrict__ wv,
                        const float* __restrict__ wo, bf16* __restrict__ dst) {
  int stride = gridDim.x * blockDim.x;
  for (int j = blockIdx.x * blockDim.x + threadIdx.x; j < N4_TOT; j += stride) {
    const float* s;
    int off;
    if (j < N4_X) { s = x; off = j; }
    else if (j < N4_X + N4_WQ) { s = wq; off = j - N4_X; }
    else if (j < N4_X + N4_WQ + N4_WK) { s = wk; off = j - (N4_X + N4_WQ); }
    else if (j < N4_X + N4_WQ + N4_WK + N4_WV) { s = wv; off = j - (N4_X + N4_WQ + N4_WK); }
    else { s = wo; off = j - (N4_X + N4_WQ + N4_WK + N4_WV); }
    float4 v = reinterpret_cast<const float4*>(s)[off];
    bf16x4 o = {(bf16)v.x, (bf16)v.y, (bf16)v.z, (bf16)v.w};
    reinterpret_cast<bf16x4*>(dst)[j] = o;
  }
}

// ---------------- GEMM: C[M,N] = A[M,K] @ B[N,K]^T (bf16 in, f32 acc) ------
// 128x128 tile, BK=32, 4 waves. This round: 2-slot dbuf (32 KB LDS) ->
// 4 blocks/CU (vs 3 with the 3-slot ring); vmcnt(0) drain per iter (m97/m99
// pattern) amortized by the extra co-resident block.
template <bool OUT_F32>
__global__ __launch_bounds__(256, 4) void gemm_bt(
    const bf16* __restrict__ A, const bf16* __restrict__ Bm,
    void* __restrict__ Cm, int M, int N, int K) {
  __shared__ __align__(16) bf16 sA[2][128 * 32];
  __shared__ __align__(16) bf16 sB[2][128 * 32];
  const int tid = threadIdx.x;
  const int row0 = blockIdx.x * 128, col0 = blockIdx.y * 128;
  const int wid = tid >> 6, lane = tid & 63;
  const int wr = wid >> 1, wc = wid & 1;
  const int l15 = lane & 15, kk = (lane >> 4) * 8;
  f32x4 acc[4][4] = {};
  const int nk = K / 32;
  const int r0 = tid >> 2, c0 = tid & 3;
  const int r1 = 64 + r0, c1 = c0;
  const int ldsA0 = (wid * 64) * 8, ldsA1 = (256 + wid * 64) * 8;

  auto stage = [&](int kt, int slot) {
    gload16(A + (size_t)(row0 + r0) * K + kt * 32 + c0 * 8, &sA[slot][ldsA0]);
    gload16(A + (size_t)(row0 + r1) * K + kt * 32 + c1 * 8, &sA[slot][ldsA1]);
    gload16(Bm + (size_t)(col0 + r0) * K + kt * 32 + c0 * 8, &sB[slot][ldsA0]);
    gload16(Bm + (size_t)(col0 + r1) * K + kt * 32 + c1 * 8, &sB[slot][ldsA1]);
  };

  stage(0, 0);
  asm volatile("s_waitcnt vmcnt(0)" ::: "memory");
  __builtin_amdgcn_s_barrier();
  __builtin_amdgcn_sched_barrier(0);

  for (int kt = 0; kt < nk; ++kt) {
    const int cur = kt & 1;
    if (kt + 1 < nk) stage(kt + 1, cur ^ 1);
    const bf16* cA = sA[cur];
    const bf16* cB = sB[cur];
    bf16x8 af[4], bfr[4];
#pragma unroll
    for (int m = 0; m < 4; ++m)
      af[m] = *reinterpret_cast<const bf16x8*>(cA + (wr * 64 + m * 16 + l15) * 32 + kk);
#pragma unroll
    for (int n = 0; n < 4; ++n)
      bfr[n] = *reinterpret_cast<const bf16x8*>(cB + (wc * 64 + n * 16 + l15) * 32 + kk);
    __builtin_amdgcn_s_setprio(1);
#pragma unroll
    for (int m = 0; m < 4; ++m)
#pragma unroll
      for (int n = 0; n < 4; ++n)
        acc[m][n] = __builtin_amdgcn_mfma_f32_16x16x32_bf16(af[m], bfr[n], acc[m][n], 0, 0, 0);
    __builtin_amdgcn_s_setprio(0);
    if (kt + 1 < nk) {
      asm volatile("s_waitcnt vmcnt(0)" ::: "memory");  // next tile landed
      __builtin_amdgcn_s_barrier();
      __builtin_amdgcn_sched_barrier(0);
    }
  }
#pragma unroll
  for (int m = 0; m < 4; ++m)
#pragma unroll
    for (int n = 0; n < 4; ++n)
#pragma unroll
      for (int r = 0; r < 4; ++r) {
        int row = row0 + wr * 64 + m * 16 + (lane >> 4) * 4 + r;
        int col = col0 + wc * 64 + n * 16 + l15;
        if constexpr (OUT_F32)
          reinterpret_cast<float*>(Cm)[(size_t)row * N + col] = acc[m][n][r];
        else
          reinterpret_cast<bf16*>(Cm)[(size_t)row * N + col] = (bf16)acc[m][n][r];
      }
}

// ------- Fused K-norm/RoPE + V-transpose (both read qkv only) --------------
// blocks [0, 4096): k_norm_rope — VECTORIZED: bf16x2 loads (elems 2l,2l+1),
//   rope partner via shfl_xor(32) (lane l^32 holds elems e±64), float2
//   weight/cos/sin loads, bf16x2 store.
// blocks [4096, 4352): v_transpose (bid-4096 -> (l0, bk))
__global__ __launch_bounds__(256) void knorm_vtrans(
    const bf16* __restrict__ proj,   // (TOK, NQKV)
    const float* __restrict__ normw,
    const float* __restrict__ cosb, const float* __restrict__ sinb,
    bf16* __restrict__ kout,         // (B,HKV,L,D)
    bf16* __restrict__ vt) {         // (B,HKV,D,L)
  __shared__ __align__(16) bf16 sT[64 * 136];
  if (blockIdx.x < 4096) {
    int gw = (blockIdx.x * blockDim.x + threadIdx.x) >> 6;
    int lane = threadIdx.x & 63;
    int head = gw & 3, tok = gw >> 2;
    int b = tok / L_, l = tok % L_;
    const bf16* p = proj + (size_t)tok * NQKV_ + H_ * D_ + head * D_;
    bf16x2 v = *reinterpret_cast<const bf16x2*>(p + 2 * lane);
    float t0 = (float)v[0], t1 = (float)v[1];
    float ss = t0 * t0 + t1 * t1;
#pragma unroll
    for (int off = 32; off; off >>= 1) ss += __shfl_xor(ss, off);
    float r = rsqrtf(ss * (1.0f / 128.0f) + 1e-6f);
    float2 w = *reinterpret_cast<const float2*>(normw + 2 * lane);
    float n0 = t0 * r * w.x, n1 = t1 * r * w.y;
    float pn0 = __shfl_xor(n0, 32);
    float pn1 = __shfl_xor(n1, 32);
    int ci = (2 * lane) & 63;
    float2 c2 = *reinterpret_cast<const float2*>(cosb + l * 64 + ci);
    float2 s2 = *reinterpret_cast<const float2*>(sinb + l * 64 + ci);
    float o0, o1;
    if (lane < 32) {  // elems e<64: n[e]*c[e] - n[e+64]*s[e]
      o0 = n0 * c2.x - pn0 * s2.x;
      o1 = n1 * c2.y - pn1 * s2.y;
    } else {          // elems e>=64, i=e-64: n[e]*c[i] + n[i]*s[i]
      o0 = n0 * c2.x + pn0 * s2.x;
      o1 = n1 * c2.y + pn1 * s2.y;
    }
    bf16x2 o = {(bf16)o0, (bf16)o1};
    bf16* q = kout + (((size_t)b * HKV_ + head) * L_ + l) * D_;
    *reinterpret_cast<bf16x2*>(q + 2 * lane) = o;
    return;
  }
  const int vbid = blockIdx.x - 4096;
  const int t = threadIdx.x;
  const int l0 = (vbid & 31) * 64;
  const int bk = vbid >> 5;  // b*HKV+h
  const bf16* src = proj + (size_t)((bk >> 2) * L_ + l0) * NQKV_ + (H_ + HKV_) * D_ + (bk & 3) * D_;
#pragma unroll
  for (int c = 0; c < 4; ++c) {
    int idx = c * 256 + t;
    int l = idx >> 4, dc = idx & 15;
    bf16x8 v = *reinterpret_cast<const bf16x8*>(src + (size_t)l * NQKV_ + dc * 8);
    *reinterpret_cast<bf16x8*>((char*)sT + l * 272 + ((dc ^ (l >> 3)) << 4)) = v;
  }
  __syncthreads();
  bf16* dst = vt + (size_t)bk * D_ * L_ + l0;
#pragma unroll
  for (int c = 0; c < 4; ++c) {
    int idx = c * 256 + t;
    int d = idx >> 3, lg = idx & 7;
    bf16x8 o;
#pragma unroll
    for (int j = 0; j < 8; ++j) {
      int l = lg * 8 + j;
      o[j] = *reinterpret_cast<const bf16*>((char*)sT + l * 272 + (((d >> 3) ^ lg) << 4) + (d & 7) * 2);
    }
    *reinterpret_cast<bf16x8*>(dst + (size_t)d * L_ + lg * 8) = o;
  }
}

// ---------------- Fused flash attention, block-causal, GQA -----------------
// R11/R15 version verbatim (best measured: 76.0 us).
#define SM_K0 0
#define SM_K1 16384
#define SM_V0 32768
#define SM_V1 49152
#define SM_P  65536
__global__ __launch_bounds__(512, 4) void attn_fused(
    const bf16* __restrict__ QKV,  // (TOK, NQKV) raw projections
    const bf16* __restrict__ Kn,   // (B,HKV,L,D) normed+roped
    const bf16* __restrict__ Vt,   // (B,HKV,D,L)
    const float* __restrict__ qnw,
    const float* __restrict__ cosb, const float* __restrict__ sinb,
    bf16* __restrict__ AO) {  // (B,L,H,D)
  __shared__ __align__(16) char smem[81920];
  const int tid = threadIdx.x;
  const int wid = tid >> 6, lane = tid & 63;
  const int bid = blockIdx.x;
  const int bk = bid & 7;  // same-bk blocks land on same XCD (bid%8)
  const int qt = (bid < 256) ? (bid >> 3) : 63 - ((bid - 256) >> 3);
  const int b = bk >> 2;
  const int hl = wid & 3, qs = wid >> 2;
  const int h = (bk & 3) * G_ + hl;
  const int qrow0 = qt * 32 + qs * 16;
  const int l15 = lane & 15, g4 = lane >> 4, kk = g4 * 8;
  const int swz = (l15 & 7) << 4;

  // ---- fused Q: load + RMSNorm + RoPE (row = qrow0 + l15) ----
  const int qrow = qrow0 + l15;
  const bf16* qsrc = QKV + (size_t)(b * L_ + qrow) * NQKV_ + h * D_;
  float t[4][8];
  float ss = 0.f;
#pragma unroll
  for (int c = 0; c < 4; ++c) {
    bf16x8 v = *reinterpret_cast<const bf16x8*>(qsrc + c * 32 + kk);
#pragma unroll
    for (int j = 0; j < 8; ++j) { t[c][j] = (float)v[j]; ss += t[c][j] * t[c][j]; }
  }

  // staging coordinates (pre-swizzled global sources, linear LDS dest)
  const int kr0 = tid >> 4, kc0 = tid & 15;
  const int kr1 = 32 + kr0;
  const int vr0 = tid >> 3, vc0 = tid & 7;
  const int vr1 = 64 + vr0;
  const bf16* kb = Kn + (size_t)bk * L_ * D_;
  const bf16* vb = Vt + (size_t)bk * D_ * (size_t)L_;
  const bf16* kp0 = kb + (size_t)kr0 * D_ + ((kc0 ^ (kr0 & 7)) * 8);
  const bf16* kp1 = kb + (size_t)kr1 * D_ + ((kc0 ^ (kr1 & 7)) * 8);
  const bf16* vp0 = vb + (size_t)vr0 * L_ + ((vc0 ^ (vr0 & 7)) * 8);
  const bf16* vp1 = vb + (size_t)vr1 * L_ + ((vc0 ^ (vr1 & 7)) * 8);

  const int ntiles = ((qt >> 3) + 1) * 4;
  gload16(kp0, smem + SM_K0 + tid * 16);
  gload16(kp1, smem + SM_K0 + 8192 + tid * 16);
  gload16(vp0, smem + SM_V0 + tid * 16);
  gload16(vp1, smem + SM_V0 + 8192 + tid * 16);

  constexpr float SCL = 0.12752650038632816f;  // 128^-0.5 * log2(e)
  ss += __shfl_xor(ss, 16);
  ss += __shfl_xor(ss, 32);
  const float rr = rsqrtf(ss * (1.0f / 128.0f) + 1e-6f);
  bf16x8 qf[4];
#pragma unroll
  for (int c = 0; c < 2; ++c)
#pragma unroll
    for (int j = 0; j < 8; ++j) {
      int i = c * 32 + kk + j;
      float n1 = t[c][j] * rr * qnw[i];
      float n2 = t[c + 2][j] * rr * qnw[i + 64];
      float cs = cosb[qrow * 64 + i], sn = sinb[qrow * 64 + i];
      qf[c][j] = (bf16)((n1 * cs - n2 * sn) * SCL);
      qf[c + 2][j] = (bf16)((n2 * cs + n1 * sn) * SCL);
    }

  // ---- loop-invariant LDS byte addresses ----
  int aK[4], aV[2], aPw[4];
#pragma unroll
  for (int c = 0; c < 4; ++c)
    aK[c] = l15 * 256 + ((((c << 2) + g4) ^ (l15 & 7)) << 4);
#pragma unroll
  for (int hh = 0; hh < 2; ++hh)
    aV[hh] = l15 * 128 + ((((hh << 2) + g4) ^ (l15 & 7)) << 4);
  const int pbase = SM_P + wid * 2048 + l15 * 128;
#pragma unroll
  for (int n = 0; n < 4; ++n)
    aPw[n] = pbase + (((n << 5) + (g4 << 3)) ^ swz);
  const int aPr0 = pbase + ((g4 << 4) ^ swz);
  const int aPr1 = pbase + ((64 + (g4 << 4)) ^ swz);

  f32x4 acc[8] = {};
  float mref = -1e30f, lpart = 0.f;

  __syncthreads();  // tile 0 staged

  auto tile_step = [&](int KB, int VB, int KBn, int VBn, int ktNext, bool doPref) {
    if (doPref) {
      gload16(kp0 + (size_t)ktNext * 64 * D_, smem + KBn + tid * 16);
      gload16(kp1 + (size_t)ktNext * 64 * D_, smem + KBn + 8192 + tid * 16);
      gload16(vp0 + ktNext * 64, smem + VBn + tid * 16);
      gload16(vp1 + ktNext * 64, smem + VBn + 8192 + tid * 16);
    }
    // --- swapped QK^T: s[n][r] = Sscaled[qrow=l15][key=16n+4g4+r] ---
    f32x4 s[4];
    __builtin_amdgcn_s_setprio(1);
#pragma unroll
    for (int n = 0; n < 4; ++n) {
      f32x4 st = {};
#pragma unroll
      for (int c = 0; c < 4; ++c) {
        bf16x8 kf = *reinterpret_cast<const bf16x8*>(smem + KB + n * 4096 + aK[c]);
        st = __builtin_amdgcn_mfma_f32_16x16x32_bf16(kf, qf[c], st, 0, 0, 0);
      }
      s[n] = st;
    }
    __builtin_amdgcn_s_setprio(0);
    // --- defer-max online softmax (scalar per lane: one q-row) ---
    float pm = fmaxf(fmaxf(s[0][0], s[0][1]), fmaxf(s[0][2], s[0][3]));
#pragma unroll
    for (int n = 1; n < 4; ++n)
      pm = fmaxf(pm, fmaxf(fmaxf(s[n][0], s[n][1]), fmaxf(s[n][2], s[n][3])));
    if (!__all(pm <= mref + 8.f)) {  // rare: true max grew -> reduce, rescale
      pm = fmaxf(pm, __shfl_xor(pm, 16));
      pm = fmaxf(pm, __shfl_xor(pm, 32));
      float mnew = fmaxf(mref, pm);
      float resc = exp2f(mref - mnew);
      mref = mnew;
      lpart *= resc;
#pragma unroll
      for (int f = 0; f < 8; ++f) acc[f] *= resc;
    }
    // --- exp2 + immediate per-quarter P write + tree row-sum ---
    float qsum[4];
#pragma unroll
    for (int n = 0; n < 4; ++n) {
      float p0 = exp2f(s[n][0] - mref);
      float p1 = exp2f(s[n][1] - mref);
      float p2 = exp2f(s[n][2] - mref);
      float p3 = exp2f(s[n][3] - mref);
      bf16x4 pw = {(bf16)p0, (bf16)p1, (bf16)p2, (bf16)p3};
      *reinterpret_cast<bf16x4*>(smem + aPw[n]) = pw;
      qsum[n] = (p0 + p1) + (p2 + p3);
    }
    lpart += (qsum[0] + qsum[1]) + (qsum[2] + qsum[3]);
    bf16x8 pf0 = *reinterpret_cast<const bf16x8*>(smem + aPr0);
    bf16x8 pf1 = *reinterpret_cast<const bf16x8*>(smem + aPr1);
    // --- PV: O^T = mfma(V^T, P^T) ---
    __builtin_amdgcn_s_setprio(1);
#pragma unroll
    for (int f = 0; f < 8; ++f) {
      bf16x8 vf0 = *reinterpret_cast<const bf16x8*>(smem + VB + f * 2048 + aV[0]);
      acc[f] = __builtin_amdgcn_mfma_f32_16x16x32_bf16(vf0, pf0, acc[f], 0, 0, 0);
      bf16x8 vf1 = *reinterpret_cast<const bf16x8*>(smem + VB + f * 2048 + aV[1]);
      acc[f] = __builtin_amdgcn_mfma_f32_16x16x32_bf16(vf1, pf1, acc[f], 0, 0, 0);
    }
    __builtin_amdgcn_s_setprio(0);
    __syncthreads();
  };

  for (int kt = 0; kt < ntiles; kt += 2) {
    tile_step(SM_K0, SM_V0, SM_K1, SM_V1, kt + 1, true);
    tile_step(SM_K1, SM_V1, SM_K0, SM_V0, kt + 2, kt + 2 < ntiles);
  }

  // --- epilogue ---
  lpart += __shfl_xor(lpart, 16);
  lpart += __shfl_xor(lpart, 32);
  const float rinv = 1.f / lpart;
  bf16* aop = AO + ((size_t)(b * L_ + qrow0 + l15) * H_ + h) * D_ + (g4 << 2);
#pragma unroll
  for (int f = 0; f < 8; ++f) {
    bf16x4 o = {(bf16)(acc[f][0] * rinv), (bf16)(acc[f][1] * rinv),
                (bf16)(acc[f][2] * rinv), (bf16)(acc[f][3] * rinv)};
    *reinterpret_cast<bf16x4*>(aop + f * 16) = o;
  }
}

// ---------------- launch ----------------
extern "C" void kernel_launch(void* const* d_in, const int* in_sizes, int n_in,
                              void* d_out, int out_size, void* d_ws, size_t ws_size,
                              hipStream_t stream) {
  const float* x = (const float*)d_in[0];
  const float* Wq = (const float*)d_in[1];
  const float* Wk = (const float*)d_in[2];
  const float* Wv = (const float*)d_in[3];
  const float* Wo = (const float*)d_in[4];
  const float* qnw = (const float*)d_in[5];
  const float* knw = (const float*)d_in[6];
  const float* rc = (const float*)d_in[7];
  const float* rs = (const float*)d_in[8];
  float* out = (float*)d_out;

  char* ws = (char*)d_ws;
  bf16* xb = (bf16*)ws;    ws += (size_t)TOK_ * C_ * 2;
  bf16* wqb = (bf16*)ws;   ws += (size_t)(H_ * D_) * C_ * 2;   // wq/wk/wv contiguous!
  bf16* wkb = (bf16*)ws;   ws += (size_t)(HKV_ * D_) * C_ * 2;
  bf16* wvb = (bf16*)ws;   ws += (size_t)(HKV_ * D_) * C_ * 2;
  bf16* wob = (bf16*)ws;   ws += (size_t)C_ * (H_ * D_) * 2;
  bf16* qkv = (bf16*)ws;   ws += (size_t)TOK_ * NQKV_ * 2;
  bf16* Kb = (bf16*)ws;    ws += (size_t)TOK_ * HKV_ * D_ * 2;
  bf16* Vtb = (bf16*)ws;   ws += (size_t)TOK_ * HKV_ * D_ * 2;
  bf16* AOb = xb;  // alias: xb dead after projection GEMM

  cvt_all<<<2048, 256, 0, stream>>>(x, Wq, Wk, Wv, Wo, xb);

  // fused QKV projection: N = 3072 (2-D grid)
  gemm_bt<false><<<dim3(TOK_ / 128, NQKV_ / 128), 256, 0, stream>>>(
      xb, wqb, qkv, TOK_, NQKV_, C_);

  // fused K-norm/RoPE (4096 blocks) + V-transpose (256 blocks)
  knorm_vtrans<<<4352, 256, 0, stream>>>(qkv, knw, rc, rs, Kb, Vtb);

  attn_fused<<<512, 512, 0, stream>>>(qkv, Kb, Vtb, qnw, rc, rs, AOb);

  gemm_bt<true><<<dim3(TOK_ / 128, C_ / 128), 256, 0, stream>>>(
      AOb, wob, out, TOK_, C_, H_ * D_);
}